// Round 1
// baseline (105.918 us; speedup 1.0000x reference)
//
#include <hip/hip_runtime.h>

#define B 32
#define L 200
#define DIN 64
#define H 64
#define A 36

// Kernel 1: h = x @ ln_w + ln_b ; ac = h @ w1a (per-j term) ; cc = h @ w1b (per-i term)
__global__ __launch_bounds__(64) void prep_kernel(
    const float* __restrict__ x, const float* __restrict__ ln_w,
    const float* __restrict__ ln_b, const float* __restrict__ w1,
    float* __restrict__ h_out, float* __restrict__ ac_out, float* __restrict__ cc_out)
{
    int bl = blockIdx.x;            // b*L + l
    int lane = threadIdx.x;         // 0..63
    const float* xrow = x + bl * DIN;
    float acc = ln_b[lane];
    #pragma unroll
    for (int d = 0; d < DIN; ++d)
        acc = fmaf(xrow[d], ln_w[d * H + lane], acc);   // xrow[d] uniform -> s_load; ln_w coalesced
    __shared__ float hrow[H];
    hrow[lane] = acc;
    h_out[bl * H + lane] = acc;
    __syncthreads();
    if (lane < A) {
        float sa = 0.f, sc = 0.f;
        #pragma unroll
        for (int hh = 0; hh < H; ++hh) {
            float hv = hrow[hh];                         // LDS broadcast
            sa = fmaf(hv, w1[hh * A + lane], sa);        // w1a
            sc = fmaf(hv, w1[(H + hh) * A + lane], sc);  // w1b
        }
        ac_out[bl * A + lane] = sa;
        cc_out[bl * A + lane] = sc;
    }
}

// Kernel 2: one block (64 threads) per (b, i).
__global__ __launch_bounds__(64) void score_kernel(
    const float* __restrict__ h, const float* __restrict__ ac,
    const float* __restrict__ cc, const float* __restrict__ w1,
    const float* __restrict__ b1, const float* __restrict__ w2,
    const float* __restrict__ b2, float* __restrict__ out)
{
    int bi = blockIdx.x;            // b*L + i
    int b  = bi / L;
    int i  = bi - b * L;
    int lane = threadIdx.x;

    __shared__ float tile[64 * 65]; // h[b, j0+r, :] at tile[r*65 + col]; stride 65 -> conflict-free
    __shared__ float slds[64];

    const float* hb      = h + (size_t)b * L * H;
    const float* hrow_i  = hb + (size_t)i * H;          // uniform address -> s_load path

    // cb[a] = cc[b,i,a] + b1[a]   (uniform values, VALU adds)
    const float* ccrow = cc + (size_t)bi * A;
    float cb[A];
    #pragma unroll
    for (int a = 0; a < A; ++a) cb[a] = ccrow[a] + b1[a];
    float b2v = b2[0];

    float out_acc = 0.f;
    int ntiles = (i + 64) / 64;     // ceil((i+1)/64)

    for (int t = 0; t < ntiles; ++t) {
        int j0 = t * 64;
        // cooperative tile load: row r, lane = column (coalesced 256B per row)
        for (int r = 0; r < 64; ++r) {
            int j = j0 + r; if (j >= L) j = L - 1;      // clamp; those j get score 0 below
            tile[r * 65 + lane] = hb[(size_t)j * H + lane];
        }
        __syncthreads();

        // cross[a] = sum_h (h_j[h]*h_i[h]) * w1c[h,a]   (lane = j within tile)
        float cross[A];
        #pragma unroll
        for (int a = 0; a < A; ++a) cross[a] = 0.f;

        for (int hh = 0; hh < H; ++hh) {
            float hj = tile[lane * 65 + hh];            // ds_read, 2 lanes/bank (free)
            float e  = hj * hrow_i[hh];                 // hrow_i uniform -> SGPR
            #pragma unroll
            for (int a = 0; a < A; ++a)
                cross[a] = fmaf(e, w1[(2 * H + hh) * A + a], cross[a]);  // w1c uniform -> SGPR
        }

        int j = j0 + lane;
        float score = 0.f;
        if (j <= i) {
            const float* acrow = ac + ((size_t)b * L + j) * A;
            #pragma unroll
            for (int a = 0; a < A; ++a) {
                float pre = cross[a] + acrow[a] + cb[a];
                float act = pre > 0.f ? pre : 0.01f * pre;
                score = fmaf(act, w2[a], score);
            }
            score += b2v;
        }
        slds[lane] = score;
        __syncthreads();

        // out_acc[h=lane] += sum_j score_j * h_j[h]
        #pragma unroll 8
        for (int r = 0; r < 64; ++r)
            out_acc = fmaf(slds[r], tile[r * 65 + lane], out_acc);
        __syncthreads();   // protect tile/slds before next iteration overwrites
    }

    out[(size_t)bi * H + lane] = out_acc;
}

extern "C" void kernel_launch(void* const* d_in, const int* in_sizes, int n_in,
                              void* d_out, int out_size, void* d_ws, size_t ws_size,
                              hipStream_t stream) {
    const float* x    = (const float*)d_in[0];
    const float* ln_w = (const float*)d_in[1];
    const float* ln_b = (const float*)d_in[2];
    const float* w1   = (const float*)d_in[3];
    const float* b1   = (const float*)d_in[4];
    const float* w2   = (const float*)d_in[5];
    const float* b2   = (const float*)d_in[6];
    float* out = (float*)d_out;

    // workspace layout: h (B*L*H) | ac (B*L*A) | cc (B*L*A)
    float* h_ws  = (float*)d_ws;
    float* ac_ws = h_ws + (size_t)B * L * H;
    float* cc_ws = ac_ws + (size_t)B * L * A;

    prep_kernel<<<B * L, 64, 0, stream>>>(x, ln_w, ln_b, w1, h_ws, ac_ws, cc_ws);
    score_kernel<<<B * L, 64, 0, stream>>>(h_ws, ac_ws, cc_ws, w1, b1, w2, b2, out);
}

// Round 2
// 87.715 us; speedup vs baseline: 1.2075x; 1.2075x over previous
//
#include <hip/hip_runtime.h>

#define B 32
#define L 200
#define DIN 64
#define H 64
#define A 36
#define IPB 4   // i-values per block, one per wave

// Kernel 1: h = x @ ln_w + ln_b ; ac = h @ w1a (j-term) ; cc = h @ w1b (i-term)
// 256 threads = 4 waves, one row per wave.
__global__ __launch_bounds__(256) void prep_kernel(
    const float* __restrict__ x, const float* __restrict__ ln_w,
    const float* __restrict__ ln_b, const float* __restrict__ w1,
    float* __restrict__ h_out, float* __restrict__ ac_out, float* __restrict__ cc_out)
{
    int wave = threadIdx.x >> 6;
    int lane = threadIdx.x & 63;
    int bl = __builtin_amdgcn_readfirstlane(blockIdx.x * IPB + wave); // b*L + l, uniform
    const float* xrow = x + (size_t)bl * DIN;                        // uniform -> s_load path
    float acc = ln_b[lane];
    #pragma unroll
    for (int d = 0; d < DIN; ++d)
        acc = fmaf(xrow[d], ln_w[d * H + lane], acc);
    __shared__ float hrow[IPB][H];
    hrow[wave][lane] = acc;
    h_out[(size_t)bl * H + lane] = acc;
    // intra-wave LDS RAW: no barrier needed
    if (lane < A) {
        float sa = 0.f, sc = 0.f;
        #pragma unroll
        for (int hh = 0; hh < H; ++hh) {
            float hv = hrow[wave][hh];
            sa = fmaf(hv, w1[hh * A + lane], sa);        // w1a
            sc = fmaf(hv, w1[(H + hh) * A + lane], sc);  // w1b
        }
        ac_out[(size_t)bl * A + lane] = sa;
        cc_out[(size_t)bl * A + lane] = sc;
    }
}

// Kernel 2: 256 threads = 4 waves; wave w handles i = ig*4 + w; shared j-tile staging.
__global__ __launch_bounds__(256) void score_kernel(
    const float* __restrict__ h, const float* __restrict__ ac,
    const float* __restrict__ cc, const float* __restrict__ w1,
    const float* __restrict__ b1, const float* __restrict__ w2,
    const float* __restrict__ b2, float* __restrict__ out)
{
    int blk = blockIdx.x;
    int b  = blk / (L / IPB);
    int ig = blk - b * (L / IPB);
    int wave = threadIdx.x >> 6;
    int lane = threadIdx.x & 63;
    int i = __builtin_amdgcn_readfirstlane(ig * IPB + wave);  // wave-uniform -> SGPR

    __shared__ float tile[64 * 65];   // h[b, j0+r, :] at tile[r*65+c]; stride 65 conflict-free
    __shared__ float slds[IPB][64];   // per-wave score row (intra-wave only)

    const float* hb    = h + (size_t)b * L * H;
    const float* hi    = hb + (size_t)i * H;                  // uniform -> s_load
    const float* ccrow = cc + ((size_t)b * L + i) * A;        // uniform -> s_load
    float b2v = b2[0];

    float out_acc = 0.f;
    int imax = ig * IPB + (IPB - 1);
    int ntiles = (imax + 64) / 64;    // ceil((imax+1)/64)

    for (int t = 0; t < ntiles; ++t) {
        int j0 = t * 64;
        // cooperative tile load: 16 rows per wave, coalesced 256B per row
        for (int r = wave; r < 64; r += IPB) {
            int j = j0 + r; if (j >= L) j = L - 1;            // clamp; masked below
            tile[r * 65 + lane] = hb[(size_t)j * H + lane];
        }
        __syncthreads();

        if (i >= j0) {                                        // wave-uniform branch
            // cross[a] = sum_h (h_j[h]*h_i[h]) * w1c[h,a], lane = j-j0
            float cross[A];
            #pragma unroll
            for (int a = 0; a < A; ++a) cross[a] = 0.f;
            #pragma unroll 4
            for (int hh = 0; hh < H; ++hh) {
                float hj = tile[lane * 65 + hh];              // 2 lanes/bank: free
                float e  = hj * hi[hh];                       // SGPR operand
                #pragma unroll
                for (int a = 0; a < A; ++a)
                    cross[a] = fmaf(e, w1[(2 * H + hh) * A + a], cross[a]); // SGPR operand
            }
            int j = j0 + lane;
            float score = 0.f;
            if (j <= i) {
                const float* acrow = ac + ((size_t)b * L + j) * A;
                #pragma unroll
                for (int a = 0; a < A; ++a) {
                    float pre = cross[a] + acrow[a] + (ccrow[a] + b1[a]); // (..) loop-invariant
                    float act = pre > 0.f ? pre : 0.01f * pre;
                    score = fmaf(act, w2[a], score);
                }
                score += b2v;
            }
            slds[wave][lane] = score;
            // same-wave LDS RAW -> compiler lgkmcnt, no barrier
            #pragma unroll 8
            for (int r = 0; r < 64; ++r)
                out_acc = fmaf(slds[wave][r], tile[r * 65 + lane], out_acc);
        }
        __syncthreads();   // protect tile before next iteration overwrites
    }

    out[((size_t)b * L + i) * H + lane] = out_acc;
}

extern "C" void kernel_launch(void* const* d_in, const int* in_sizes, int n_in,
                              void* d_out, int out_size, void* d_ws, size_t ws_size,
                              hipStream_t stream) {
    const float* x    = (const float*)d_in[0];
    const float* ln_w = (const float*)d_in[1];
    const float* ln_b = (const float*)d_in[2];
    const float* w1   = (const float*)d_in[3];
    const float* b1   = (const float*)d_in[4];
    const float* w2   = (const float*)d_in[5];
    const float* b2   = (const float*)d_in[6];
    float* out = (float*)d_out;

    float* h_ws  = (float*)d_ws;
    float* ac_ws = h_ws + (size_t)B * L * H;
    float* cc_ws = ac_ws + (size_t)B * L * A;

    prep_kernel<<<(B * L) / IPB, 256, 0, stream>>>(x, ln_w, ln_b, w1, h_ws, ac_ws, cc_ws);
    score_kernel<<<B * (L / IPB), 256, 0, stream>>>(h_ws, ac_ws, cc_ws, w1, b1, w2, b2, out);
}

// Round 3
// 57.167 us; speedup vs baseline: 1.8528x; 1.5344x over previous
//
#include <hip/hip_runtime.h>

#define B 32
#define L 200
#define DIN 64
#define H 64
#define A 36
#define IPB 4   // i-values per block, one per wave

typedef __attribute__((ext_vector_type(8))) short short8;   // bf16 MFMA fragment
typedef __attribute__((ext_vector_type(4))) float floatx4;  // MFMA accumulator

static __device__ __forceinline__ short f2bf(float f) {
    union { float f; unsigned u; } v; v.f = f;
    unsigned r = (v.u + 0x7FFF + ((v.u >> 16) & 1)) >> 16;  // RNE
    return (short)r;
}
static __device__ __forceinline__ float bf2f(short s) {
    union { unsigned u; float f; } v; v.u = ((unsigned)(unsigned short)s) << 16;
    return v.f;
}

// Kernel 1: h = x@ln_w + ln_b ; store h (f32), h_bf16 pre-swizzled, cc = h@w1b.
__global__ __launch_bounds__(256) void prep_kernel(
    const float* __restrict__ x, const float* __restrict__ ln_w,
    const float* __restrict__ ln_b, const float* __restrict__ w1,
    float* __restrict__ h_out, float* __restrict__ cc_out, short* __restrict__ hb16_out)
{
    int wave = threadIdx.x >> 6;
    int lane = threadIdx.x & 63;
    int bl = __builtin_amdgcn_readfirstlane(blockIdx.x * IPB + wave);
    const float* xrow = x + (size_t)bl * DIN;
    float acc = ln_b[lane];
    #pragma unroll
    for (int d = 0; d < DIN; ++d)
        acc = fmaf(xrow[d], ln_w[d * H + lane], acc);
    __shared__ float hrow[IPB][H];
    hrow[wave][lane] = acc;
    h_out[(size_t)bl * H + lane] = acc;
    int j = bl % L;
    // pre-swizzled bf16: at read time tile row r (= j mod 64) uses byte^((r&7)<<4)
    hb16_out[(size_t)bl * H + (lane ^ ((j & 7) << 3))] = f2bf(acc);
    if (lane < A) {
        float sc = 0.f;
        #pragma unroll
        for (int hh = 0; hh < H; ++hh)
            sc = fmaf(hrow[wave][hh], w1[(H + hh) * A + lane], sc);  // w1b
        cc_out[(size_t)bl * A + lane] = sc;
    }
}

// Kernel 2: 4 waves/block, wave w owns i = ig*4+w. Cross GEMM on MFMA.
__global__ __launch_bounds__(256) void score_kernel(
    const float* __restrict__ h, const short* __restrict__ hb16,
    const float* __restrict__ cc, const float* __restrict__ w1,
    const float* __restrict__ b1, const float* __restrict__ w2,
    const float* __restrict__ b2, float* __restrict__ out)
{
    int blk = blockIdx.x;
    int b  = blk / (L / IPB);
    int ig = blk - b * (L / IPB);
    int wave = threadIdx.x >> 6;
    int lane = threadIdx.x & 63;
    int i = __builtin_amdgcn_readfirstlane(ig * IPB + wave);
    int l15 = lane & 15, l4 = lane >> 4;

    __shared__ __align__(16) short tile[64 * 64];   // bf16, rows swizzled (pre-swizzled global)
    __shared__ __align__(16) float slds[IPB][68];

    const short* hb16b = hb16 + (size_t)b * L * H;
    const float* hi    = h + ((size_t)b * L + i) * H;     // uniform -> s_load path
    const float* ccrow = cc + ((size_t)b * L + i) * A;

    // ---- per-wave constants: B_i fragments, cb, w2 ----
    float cbv[3], w2v[3];
    #pragma unroll
    for (int n = 0; n < 3; ++n) {
        int c = n * 16 + l15;
        bool cv = c < A;
        cbv[n] = cv ? (ccrow[c] + b1[c]) : 0.f;
        w2v[n] = cv ? w2[c] : 0.f;
    }
    short8 bfrag[2][3];
    #pragma unroll
    for (int s = 0; s < 2; ++s) {
        float hik[8];
        #pragma unroll
        for (int e = 0; e < 8; ++e) hik[e] = hi[s * 32 + l4 * 8 + e];
        #pragma unroll
        for (int n = 0; n < 3; ++n) {
            int c = n * 16 + l15;
            bool cv = c < A;
            #pragma unroll
            for (int e = 0; e < 8; ++e) {
                int k = s * 32 + l4 * 8 + e;
                float wc = cv ? w1[(2 * H + k) * A + c] : 0.f;  // w1c
                float wa = cv ? w1[k * A + c] : 0.f;            // w1a
                bfrag[s][n][e] = f2bf(fmaf(hik[e], wc, wa));
            }
        }
    }
    float b2v = b2[0];
    float out_acc = 0.f;
    int imax = ig * IPB + (IPB - 1);
    int ntiles = (imax + 64) / 64;

    for (int t = 0; t < ntiles; ++t) {
        int j0 = t * 64;
        // ---- stage tile: wave w copies rows w*16..w*16+15 (linear, pre-swizzled) ----
        #pragma unroll
        for (int it = 0; it < 2; ++it) {
            int r = wave * 16 + it * 8 + (lane >> 3);
            int j = j0 + r; if (j > L - 1) j = L - 1;
            const int4* src = (const int4*)(hb16b + (size_t)j * H) + (lane & 7);
            *((int4*)tile + r * 8 + (lane & 7)) = *src;    // ds_write_b128, conflict-free
        }
        __syncthreads();

        int irel = i - j0;
        if (irel >= 0) {                                   // wave-uniform
            int mmax = ((irel < 63 ? irel : 63) >> 4) + 1;
            for (int m = 0; m < mmax; ++m) {
                int row = m * 16 + l15;
                const short* arow = tile + row * H;
                int sw = (row & 7) << 3;
                short8 af0 = *(const short8*)(arow + ((0  + l4 * 8) ^ sw));
                short8 af1 = *(const short8*)(arow + ((32 + l4 * 8) ^ sw));
                floatx4 a0 = {cbv[0], cbv[0], cbv[0], cbv[0]};
                floatx4 a1 = {cbv[1], cbv[1], cbv[1], cbv[1]};
                floatx4 a2 = {cbv[2], cbv[2], cbv[2], cbv[2]};
                a0 = __builtin_amdgcn_mfma_f32_16x16x32_bf16(af0, bfrag[0][0], a0, 0, 0, 0);
                a1 = __builtin_amdgcn_mfma_f32_16x16x32_bf16(af0, bfrag[0][1], a1, 0, 0, 0);
                a2 = __builtin_amdgcn_mfma_f32_16x16x32_bf16(af0, bfrag[0][2], a2, 0, 0, 0);
                a0 = __builtin_amdgcn_mfma_f32_16x16x32_bf16(af1, bfrag[1][0], a0, 0, 0, 0);
                a1 = __builtin_amdgcn_mfma_f32_16x16x32_bf16(af1, bfrag[1][1], a1, 0, 0, 0);
                a2 = __builtin_amdgcn_mfma_f32_16x16x32_bf16(af1, bfrag[1][2], a2, 0, 0, 0);
                // epilogue: leaky + w2, reduce over a (lanes l&15), scatter scores to slds
                float sp[4];
                #pragma unroll
                for (int r = 0; r < 4; ++r) {
                    float v0 = a0[r], v1 = a1[r], v2 = a2[r];
                    v0 = v0 > 0.f ? v0 : 0.01f * v0;
                    v1 = v1 > 0.f ? v1 : 0.01f * v1;
                    v2 = v2 > 0.f ? v2 : 0.01f * v2;
                    sp[r] = v0 * w2v[0] + v1 * w2v[1] + v2 * w2v[2];
                }
                #pragma unroll
                for (int d = 1; d < 16; d <<= 1) {
                    #pragma unroll
                    for (int r = 0; r < 4; ++r) sp[r] += __shfl_xor(sp[r], d, 64);
                }
                if (l15 == 0) {
                    #pragma unroll
                    for (int r = 0; r < 4; ++r) {
                        int jt = m * 16 + l4 * 4 + r;
                        slds[wave][jt] = (jt <= irel) ? sp[r] + b2v : 0.f;
                    }
                }
            }
            // ---- PV: out_acc[h=lane] += score_r * h_tile[r][lane] ----
            int rmax = irel < 63 ? irel : 63;
            for (int rb = 0; rb <= rmax; rb += 4) {
                floatx4 sv = *(const floatx4*)&slds[wave][rb];   // same-addr broadcast
                #pragma unroll
                for (int q = 0; q < 4; ++q) {
                    int r = rb + q;
                    if (r > rmax) break;
                    short hbv = tile[r * H + (lane ^ ((r & 7) << 3))];
                    out_acc = fmaf(sv[q], bf2f(hbv), out_acc);
                }
            }
        }
        __syncthreads();   // protect tile before next staging
    }

    out[((size_t)b * L + i) * H + lane] = out_acc;
}

extern "C" void kernel_launch(void* const* d_in, const int* in_sizes, int n_in,
                              void* d_out, int out_size, void* d_ws, size_t ws_size,
                              hipStream_t stream) {
    const float* x    = (const float*)d_in[0];
    const float* ln_w = (const float*)d_in[1];
    const float* ln_b = (const float*)d_in[2];
    const float* w1   = (const float*)d_in[3];
    const float* b1   = (const float*)d_in[4];
    const float* w2   = (const float*)d_in[5];
    const float* b2   = (const float*)d_in[6];
    float* out = (float*)d_out;

    float* h_ws  = (float*)d_ws;                       // B*L*H f32
    float* cc_ws = h_ws + (size_t)B * L * H;           // B*L*A f32
    short* hb16_ws = (short*)(cc_ws + (size_t)B * L * A); // B*L*H bf16 (pre-swizzled)

    prep_kernel<<<(B * L) / IPB, 256, 0, stream>>>(x, ln_w, ln_b, w1, h_ws, cc_ws, hb16_ws);
    score_kernel<<<B * (L / IPB), 256, 0, stream>>>(h_ws, hb16_ws, cc_ws, w1, b1, w2, b2, out);
}